// Round 8
// baseline (99.385 us; speedup 1.0000x reference)
//
#include <hip/hip_runtime.h>
#include <hip/hip_bf16.h>
#include <stdint.h>

// ConstrastiveLoss2: loss = (sum_i lse_row(i) + sum_j lse_col(j) - 2*tau*sum_e a[e]b[e]) / (2B)
// logits = tau * ftir @ raman^T, tau = min(exp(log_tau), 100), B=4096, D=512.
// R8: fat wave tile. Block 256x128 (4 waves 2x2), wave 128x64 via 8x4 of
// 16x16x32 MFMA (acc 128 VGPR). 12 ds_read_b128 per 32 MFMAs = 42.7 FLOP/LDS-B
// (-25% LDS read traffic, the binding resource per R6/R7 evidence). 512 blocks,
// 2/CU, BK=32 dbuf (48KB). Row epilogue in 2 phases; col partials 16 chunks.

typedef float f32x4 __attribute__((ext_vector_type(4)));
typedef __bf16 bf16x8 __attribute__((ext_vector_type(8)));
typedef __bf16 bf16x4 __attribute__((ext_vector_type(4)));

#define B_DIM 4096
#define D_DIM 512
#define NCHUNK_R 32   // row partial chunks (one per bn block)
#define NCHUNK_C 16   // col partial chunks (one per bm block)

__device__ __forceinline__ void gld_lds16(const void* g, void* l) {
  __builtin_amdgcn_global_load_lds(
      (const __attribute__((address_space(1))) unsigned int*)g,
      (__attribute__((address_space(3))) unsigned int*)l,
      16, 0, 0);
}

// ---------------- cast fp32 -> bf16 (4-block XOR swizzle) + fused diag partials ----------------
// Within each row's aligned 64B group (4 x 16B blocks), logical block g is
// stored at physical position g ^ ((row>>1)&3). Also zeroes acc + counter.
__global__ __launch_bounds__(256) void cast_diag_kernel(
    const float* __restrict__ A, const float* __restrict__ Bm,
    __bf16* __restrict__ Abf, __bf16* __restrict__ Bbf,
    float* __restrict__ diagp, float* __restrict__ acc,
    unsigned* __restrict__ counter) {
  if (blockIdx.x == 0 && threadIdx.x == 0) { acc[0] = 0.f; counter[0] = 0u; }
  const float4* A4 = (const float4*)A;
  const float4* B4 = (const float4*)Bm;
  bf16x4* Ab4 = (bf16x4*)Abf;
  bf16x4* Bb4 = (bf16x4*)Bbf;
  int idx = blockIdx.x * 256 + threadIdx.x;
  float local = 0.f;
  #pragma unroll
  for (int it = 0; it < 4; ++it, idx += 512 * 256) {
    int row = idx >> 7, el4 = idx & 127;      // el4: [6:3]=64B group [2:1]=g [0]=8B half
    int g = (el4 >> 1) & 3;
    int gswz = g ^ ((row >> 1) & 3);
    int el4p = (el4 & ~6) | (gswz << 1);
    int pidx = row * 128 + el4p;
    float4 va = A4[idx], vb = B4[idx];
    bf16x4 oa, ob;
    oa[0] = (__bf16)va.x; oa[1] = (__bf16)va.y; oa[2] = (__bf16)va.z; oa[3] = (__bf16)va.w;
    ob[0] = (__bf16)vb.x; ob[1] = (__bf16)vb.y; ob[2] = (__bf16)vb.z; ob[3] = (__bf16)vb.w;
    Ab4[pidx] = oa; Bb4[pidx] = ob;
    local += va.x*vb.x + va.y*vb.y + va.z*vb.z + va.w*vb.w;
  }
  #pragma unroll
  for (int off = 1; off < 64; off <<= 1) local += __shfl_xor(local, off);
  __shared__ float red[4];
  int w = threadIdx.x >> 6, lane = threadIdx.x & 63;
  if (lane == 0) red[w] = local;
  __syncthreads();
  if (threadIdx.x == 0)
    diagp[blockIdx.x] = red[0] + red[1] + red[2] + red[3];
}

// ---------------- fused GEMM + per-tile row/col (max, sumexp) partials ----------------
// 512 blocks (XCD-swizzled); block tile 256x128, 4 waves 2x2; wave 128x64 via
// 8x4 of 16x16x32 MFMA. BK=32, double-buffered async DMA staging.
__global__ __launch_bounds__(256, 2) void gemm_lse_kernel(
    const __bf16* __restrict__ A, const __bf16* __restrict__ Bm,
    const float* __restrict__ log_tau,
    float* __restrict__ row_pmax, float* __restrict__ row_psum,
    float* __restrict__ col_pmax, float* __restrict__ col_psum) {
  __shared__ char smem[49152];                 // 2 stages x (A 16KB + B 8KB); epilogue overlay
  // XCD swizzle: blk%8 ~ XCD id; each XCD gets a 4(bm) x 16(bn) cluster
  // (A 4x256K + B 16x128K = 3MB < 4MB L2).
  const int blk = blockIdx.x;
  const int xcd = blk & 7, loc = blk >> 3;     // loc 0..63
  const int bm = (xcd & 3) * 4 + (loc & 3);    // 0..15 (256-row panels)
  const int bn = (xcd >> 2) * 16 + (loc >> 2); // 0..31 (128-col panels)
  const int t = threadIdx.x;
  const int lane = t & 63;
  const int w = t >> 6;
  const int wm = (w >> 1) * 128, wn = (w & 1) * 64;
  const int q = lane >> 4, c16 = lane & 15;
  const int kbs = q ^ ((c16 >> 1) & 3);        // physical 16B-block for this lane

  f32x4 acc[8][4] = {};

  // staging: thread t -> row (t>>2)+64*i, 16B-block t&3 of the 64B row-group
  const char* Ag = (const char*)A + (size_t)(bm * 256 + (t >> 2)) * 1024 + (t & 3) * 16;
  const char* Bg = (const char*)Bm + (size_t)(bn * 128 + (t >> 2)) * 1024 + (t & 3) * 16;

  // issue one BK=32 stage's DMA into buffer p (linear, lane-contiguous)
  #define ISSUE_STAGE(kt, p)                                                  \
    do {                                                                      \
      const char* ag = Ag + (kt) * 64;                                        \
      const char* bg = Bg + (kt) * 64;                                        \
      char* Al = smem + (p) * 24576 + t * 16;                                 \
      char* Bl = smem + (p) * 24576 + 16384 + t * 16;                         \
      _Pragma("unroll")                                                       \
      for (int i = 0; i < 4; ++i) gld_lds16(ag + i * 65536, Al + i * 4096);   \
      _Pragma("unroll")                                                       \
      for (int i = 0; i < 2; ++i) gld_lds16(bg + i * 65536, Bl + i * 4096);   \
    } while (0)

  ISSUE_STAGE(0, 0);
  for (int kt = 0; kt < 16; ++kt) {
    __syncthreads();                           // vmcnt(0) drain: completes buf[kt&1] DMA
    if (kt < 15) ISSUE_STAGE(kt + 1, (kt + 1) & 1);   // in flight during compute below
    const char* Ab = smem + (kt & 1) * 24576;
    const char* Bb = Ab + 16384;
    bf16x8 af[8], bfr[4];
    #pragma unroll
    for (int mi = 0; mi < 8; ++mi)
      af[mi] = *(const bf16x8*)(Ab + (wm + mi * 16 + c16) * 64 + kbs * 16);
    #pragma unroll
    for (int ni = 0; ni < 4; ++ni)
      bfr[ni] = *(const bf16x8*)(Bb + (wn + ni * 16 + c16) * 64 + kbs * 16);
    #pragma unroll
    for (int mi = 0; mi < 8; ++mi)
      #pragma unroll
      for (int ni = 0; ni < 4; ++ni)
        acc[mi][ni] = __builtin_amdgcn_mfma_f32_16x16x32_bf16(af[mi], bfr[ni], acc[mi][ni], 0, 0, 0);
  }
  __syncthreads();                             // all compute reads done before smem reuse
  #undef ISSUE_STAGE

  const float tau = fminf(__expf(log_tau[0]), 100.0f);
  #pragma unroll
  for (int mi = 0; mi < 8; ++mi)
    #pragma unroll
    for (int ni = 0; ni < 4; ++ni)
      acc[mi][ni] *= tau;

  // C layout (m89): col = wn + ni*16 + c16, row = wm + mi*16 + q*4 + r.
  // ---- rows: 2 phases of 128 rows (rbuf[128][33] float2 = 33.8KB overlay) ----
  float2* rbuf = (float2*)smem;
  #pragma unroll
  for (int p = 0; p < 2; ++p) {
    #pragma unroll
    for (int m4 = 0; m4 < 4; ++m4) {
      int mi = p * 4 + m4;
      #pragma unroll
      for (int r = 0; r < 4; ++r) {
        float v0 = acc[mi][0][r], v1 = acc[mi][1][r], v2 = acc[mi][2][r], v3 = acc[mi][3][r];
        float m = fmaxf(fmaxf(v0, v1), fmaxf(v2, v3));
        float s = __expf(v0 - m) + __expf(v1 - m) + __expf(v2 - m) + __expf(v3 - m);
        int lrow = (w >> 1) * 64 + m4 * 16 + q * 4 + r;   // 0..127 within phase
        rbuf[lrow * 33 + (w & 1) * 16 + c16] = make_float2(m, s);
      }
    }
    __syncthreads();
    if (t < 128) {
      float M = rbuf[t * 33].x;
      #pragma unroll
      for (int x = 1; x < 32; ++x) M = fmaxf(M, rbuf[t * 33 + x].x);
      float S = 0.f;
      #pragma unroll
      for (int x = 0; x < 32; ++x) { float2 pp = rbuf[t * 33 + x]; S += pp.y * __expf(pp.x - M); }
      int grow = bm * 256 + (t >> 6) * 128 + p * 64 + (t & 63);
      row_pmax[bn * B_DIM + grow] = M;         // chunk = bn (32 chunks)
      row_psum[bn * B_DIM + grow] = S;
    }
    __syncthreads();
  }
  // ---- cols: in-lane reduce over 32 (mi,r) values -> cbuf[128][9] ----
  float2* cbuf = (float2*)smem;
  #pragma unroll
  for (int ni = 0; ni < 4; ++ni) {
    float m = -3.0e38f;
    #pragma unroll
    for (int mi = 0; mi < 8; ++mi)
      #pragma unroll
      for (int r = 0; r < 4; ++r) m = fmaxf(m, acc[mi][ni][r]);
    float s = 0.f;
    #pragma unroll
    for (int mi = 0; mi < 8; ++mi)
      #pragma unroll
      for (int r = 0; r < 4; ++r) s += __expf(acc[mi][ni][r] - m);
    int c = wn + ni * 16 + c16;                // 0..127
    cbuf[c * 9 + (w >> 1) * 4 + q] = make_float2(m, s);
  }
  __syncthreads();
  if (t < 128) {
    float M = cbuf[t * 9].x;
    #pragma unroll
    for (int y = 1; y < 8; ++y) M = fmaxf(M, cbuf[t * 9 + y].x);
    float S = 0.f;
    #pragma unroll
    for (int y = 0; y < 8; ++y) { float2 pp = cbuf[t * 9 + y]; S += pp.y * __expf(pp.x - M); }
    col_pmax[bm * B_DIM + bn * 128 + t] = M;   // chunk = bm (16 chunks)
    col_psum[bm * B_DIM + bn * 128 + t] = S;
  }
}

// ---------------- combine: thread per item; last block (counter) writes d_out ----------------
__global__ __launch_bounds__(256) void combine_kernel(
    const float* __restrict__ row_pmax, const float* __restrict__ row_psum,
    const float* __restrict__ col_pmax, const float* __restrict__ col_psum,
    const float* __restrict__ diagp, const float* __restrict__ log_tau,
    float* __restrict__ acc, unsigned* __restrict__ counter,
    float* __restrict__ out) {
  const int t = threadIdx.x;
  const int item = blockIdx.x * 256 + t;       // 0..4095 rows, 4096..8191 cols
  float local;
  if (item < B_DIM) {                          // rows: 32 chunks
    const int i = item;
    float M = row_pmax[i];
    #pragma unroll
    for (int k = 1; k < NCHUNK_R; ++k) M = fmaxf(M, row_pmax[k * B_DIM + i]);
    float S = 0.f;
    #pragma unroll
    for (int k = 0; k < NCHUNK_R; ++k)
      S += row_psum[k * B_DIM + i] * __expf(row_pmax[k * B_DIM + i] - M);
    local = M + __logf(S);
  } else {                                     // cols: 16 chunks
    const int i = item - B_DIM;
    float M = col_pmax[i];
    #pragma unroll
    for (int k = 1; k < NCHUNK_C; ++k) M = fmaxf(M, col_pmax[k * B_DIM + i]);
    float S = 0.f;
    #pragma unroll
    for (int k = 0; k < NCHUNK_C; ++k)
      S += col_psum[k * B_DIM + i] * __expf(col_pmax[k * B_DIM + i] - M);
    local = M + __logf(S);
  }
  if (blockIdx.x == 0) {                       // fold diag partials (512) into block 0
    float tau = fminf(__expf(log_tau[0]), 100.0f);
    local += -2.0f * tau * (diagp[t] + diagp[t + 256]);
  }
  #pragma unroll
  for (int off = 1; off < 64; off <<= 1) local += __shfl_xor(local, off);
  __shared__ float red[4];
  int w = t >> 6, lane = t & 63;
  if (lane == 0) red[w] = local;
  __syncthreads();
  if (t == 0) {
    atomicAdd(acc, red[0] + red[1] + red[2] + red[3]);
    __threadfence();
    unsigned old = atomicAdd(counter, 1u);
    if (old == 31u) {                          // last of the 32 blocks: finalize
      float v = atomicAdd(acc, 0.0f);          // coherent read after all adds
      out[0] = v * (1.0f / 8192.0f);
    }
  }
}

// ---------------- launch ----------------
extern "C" void kernel_launch(void* const* d_in, const int* in_sizes, int n_in,
                              void* d_out, int out_size, void* d_ws, size_t ws_size,
                              hipStream_t stream) {
  const float* ftir    = (const float*)d_in[0];
  const float* raman   = (const float*)d_in[1];
  // d_in[2] = labels (int64) — unused by the reference output
  const float* log_tau = (const float*)d_in[3];
  float* out = (float*)d_out;

  char* ws = (char*)d_ws;
  // ws layout: Abf 4MiB | Bbf 4MiB | row_pmax 512K | row_psum 512K |
  //            col_pmax 512K | col_psum 512K | diagp 2K | acc 4B | counter 4B
  __bf16* Abf     = (__bf16*)(ws);
  __bf16* Bbf     = (__bf16*)(ws + (4u << 20));
  float* row_pmax = (float*)(ws + (8u << 20));
  float* row_psum = (float*)(ws + (8u << 20) + (512u << 10));
  float* col_pmax = (float*)(ws + (9u << 20));
  float* col_psum = (float*)(ws + (9u << 20) + (512u << 10));
  float* diagp    = (float*)(ws + (10u << 20));
  float* acc      = (float*)(ws + (10u << 20) + 4096);
  unsigned* cnt   = (unsigned*)(ws + (10u << 20) + 4096 + 4);

  cast_diag_kernel<<<512, 256, 0, stream>>>(ftir, raman, Abf, Bbf, diagp, acc, cnt);
  gemm_lse_kernel<<<512, 256, 0, stream>>>(Abf, Bbf, log_tau,
                                           row_pmax, row_psum, col_pmax, col_psum);
  combine_kernel<<<32, 256, 0, stream>>>(row_pmax, row_psum, col_pmax, col_psum,
                                         diagp, log_tau, acc, cnt, out);
}

// Round 9
// 96.820 us; speedup vs baseline: 1.0265x; 1.0265x over previous
//
#include <hip/hip_runtime.h>
#include <hip/hip_bf16.h>
#include <stdint.h>

// ConstrastiveLoss2: loss = (sum_i lse_row(i) + sum_j lse_col(j) - 2*tau*sum_e a[e]b[e]) / (2B)
// logits = tau * ftir @ raman^T, tau = min(exp(log_tau), 100), B=4096, D=512.
// R9: true K-loop pipeline. 3-deep BK=32 LDS stages (48KB), raw s_barrier +
// manual `s_waitcnt vmcnt(4)` (never drains the in-flight prefetch), stage k+2
// issued after the barrier (overwrite-safe). Compute identical to R7 (verified).

typedef float f32x4 __attribute__((ext_vector_type(4)));
typedef __bf16 bf16x8 __attribute__((ext_vector_type(8)));
typedef __bf16 bf16x4 __attribute__((ext_vector_type(4)));

#define B_DIM 4096
#define D_DIM 512
#define NCHUNK 32   // partial chunks per row/col (one per 128-tile in the other dim)

__device__ __forceinline__ void gld_lds16(const void* g, void* l) {
  __builtin_amdgcn_global_load_lds(
      (const __attribute__((address_space(1))) unsigned int*)g,
      (__attribute__((address_space(3))) unsigned int*)l,
      16, 0, 0);
}

// ---------------- cast fp32 -> bf16 (4-block XOR swizzle) + fused diag partials ----------------
// Within each row's aligned 64B group (4 x 16B blocks), logical block g is
// stored at physical position g ^ ((row>>1)&3). Also zeroes acc + counter.
__global__ __launch_bounds__(256) void cast_diag_kernel(
    const float* __restrict__ A, const float* __restrict__ Bm,
    __bf16* __restrict__ Abf, __bf16* __restrict__ Bbf,
    float* __restrict__ diagp, float* __restrict__ acc,
    unsigned* __restrict__ counter) {
  if (blockIdx.x == 0 && threadIdx.x == 0) { acc[0] = 0.f; counter[0] = 0u; }
  const float4* A4 = (const float4*)A;
  const float4* B4 = (const float4*)Bm;
  bf16x4* Ab4 = (bf16x4*)Abf;
  bf16x4* Bb4 = (bf16x4*)Bbf;
  int idx = blockIdx.x * 256 + threadIdx.x;
  float local = 0.f;
  #pragma unroll
  for (int it = 0; it < 4; ++it, idx += 512 * 256) {
    int row = idx >> 7, el4 = idx & 127;      // el4: [6:3]=64B group [2:1]=g [0]=8B half
    int g = (el4 >> 1) & 3;
    int gswz = g ^ ((row >> 1) & 3);
    int el4p = (el4 & ~6) | (gswz << 1);
    int pidx = row * 128 + el4p;
    float4 va = A4[idx], vb = B4[idx];
    bf16x4 oa, ob;
    oa[0] = (__bf16)va.x; oa[1] = (__bf16)va.y; oa[2] = (__bf16)va.z; oa[3] = (__bf16)va.w;
    ob[0] = (__bf16)vb.x; ob[1] = (__bf16)vb.y; ob[2] = (__bf16)vb.z; ob[3] = (__bf16)vb.w;
    Ab4[pidx] = oa; Bb4[pidx] = ob;
    local += va.x*vb.x + va.y*vb.y + va.z*vb.z + va.w*vb.w;
  }
  #pragma unroll
  for (int off = 1; off < 64; off <<= 1) local += __shfl_xor(local, off);
  __shared__ float red[4];
  int w = threadIdx.x >> 6, lane = threadIdx.x & 63;
  if (lane == 0) red[w] = local;
  __syncthreads();
  if (threadIdx.x == 0)
    diagp[blockIdx.x] = red[0] + red[1] + red[2] + red[3];
}

// ---------------- fused GEMM + per-tile row/col (max, sumexp) partials ----------------
// 1024 blocks (XCD-swizzled); 4 waves in 2x2; wave computes 64x64 via 4x4 of
// 16x16x32 MFMA. BK=32, 3-stage pipelined async DMA; 3 blocks/CU.
__global__ __launch_bounds__(256, 3) void gemm_lse_kernel(
    const __bf16* __restrict__ A, const __bf16* __restrict__ Bm,
    const float* __restrict__ log_tau,
    float* __restrict__ row_pmax, float* __restrict__ row_psum,
    float* __restrict__ col_pmax, float* __restrict__ col_psum) {
  __shared__ char smem[49152];                 // 3 stages x (A 8KB + B 8KB); epilogue overlay
  // XCD swizzle: blk%8 ~ XCD id; each XCD gets an 8(bm) x 16(bn) cluster.
  const int blk = blockIdx.x;
  const int xcd = blk & 7, loc = blk >> 3;
  const int bm = (xcd & 3) * 8 + (loc & 7);
  const int bn = (xcd >> 2) * 16 + (loc >> 3);
  const int t = threadIdx.x;
  const int lane = t & 63;
  const int w = t >> 6;
  const int wm = (w >> 1) * 64, wn = (w & 1) * 64;
  const int q = lane >> 4, c16 = lane & 15;
  const int kbs = q ^ ((c16 >> 1) & 3);        // physical 16B-block for this lane

  f32x4 acc[4][4] = {};

  // staging: thread t -> row (t>>2)+64*i, 16B-block t&3 of the stage's 64B row-group
  const char* Ag = (const char*)A + (size_t)(bm * 128 + (t >> 2)) * 1024 + (t & 3) * 16;
  const char* Bg = (const char*)Bm + (size_t)(bn * 128 + (t >> 2)) * 1024 + (t & 3) * 16;

  // issue one BK=32 stage's DMA into buffer p (linear, lane-contiguous; 4 instr -> vmcnt 4)
  #define ISSUE_STAGE(kt, p)                                                  \
    do {                                                                      \
      const char* ag = Ag + (kt) * 64;                                        \
      const char* bg = Bg + (kt) * 64;                                        \
      char* Al = smem + (p) * 16384 + t * 16;                                 \
      char* Bl = smem + (p) * 16384 + 8192 + t * 16;                          \
      _Pragma("unroll")                                                       \
      for (int i = 0; i < 2; ++i) {                                           \
        gld_lds16(ag + i * 65536, Al + i * 4096);                             \
        gld_lds16(bg + i * 65536, Bl + i * 4096);                             \
      }                                                                       \
    } while (0)

  #define COMPUTE(p)                                                          \
    do {                                                                      \
      const char* Ab = smem + (p) * 16384;                                    \
      const char* Bb = Ab + 8192;                                             \
      bf16x8 af[4], bfr[4];                                                   \
      _Pragma("unroll")                                                       \
      for (int mi = 0; mi < 4; ++mi)                                          \
        af[mi] = *(const bf16x8*)(Ab + (wm + mi * 16 + c16) * 64 + kbs * 16); \
      _Pragma("unroll")                                                       \
      for (int ni = 0; ni < 4; ++ni)                                          \
        bfr[ni] = *(const bf16x8*)(Bb + (wn + ni * 16 + c16) * 64 + kbs * 16);\
      _Pragma("unroll")                                                       \
      for (int mi = 0; mi < 4; ++mi)                                          \
        _Pragma("unroll")                                                     \
        for (int ni = 0; ni < 4; ++ni)                                        \
          acc[mi][ni] = __builtin_amdgcn_mfma_f32_16x16x32_bf16(              \
              af[mi], bfr[ni], acc[mi][ni], 0, 0, 0);                         \
    } while (0)

  ISSUE_STAGE(0, 0);
  ISSUE_STAGE(1, 1);
  for (int kt = 0; kt < 15; ++kt) {
    // stage kt landed when <=4 VMEM remain (stage kt+1 stays in flight)
    asm volatile("s_waitcnt vmcnt(4)" ::: "memory");
    __builtin_amdgcn_s_barrier();              // raw: no vmcnt(0) drain
    asm volatile("" ::: "memory");             // keep ds_reads below the barrier
    if (kt < 14) ISSUE_STAGE(kt + 2, (kt + 2) % 3);  // overwrites buf (kt-1)%3: readers done
    COMPUTE(kt % 3);
  }
  asm volatile("s_waitcnt vmcnt(0)" ::: "memory");   // last stage (15) fully landed
  __builtin_amdgcn_s_barrier();
  asm volatile("" ::: "memory");
  COMPUTE(15 % 3);
  __syncthreads();                             // full drain before epilogue smem overlay
  #undef ISSUE_STAGE
  #undef COMPUTE

  const float tau = fminf(__expf(log_tau[0]), 100.0f);
  #pragma unroll
  for (int mi = 0; mi < 4; ++mi)
    #pragma unroll
    for (int ni = 0; ni < 4; ++ni)
      acc[mi][ni] *= tau;

  // C layout (m89): col = wn + ni*16 + c16, row = wm + mi*16 + q*4 + r.
  // ---- rows phase 1: per-lane reduce over 4 ni values, scatter to rowbuf[128][33] ----
  float2* rbuf = (float2*)smem;
  #pragma unroll
  for (int mi = 0; mi < 4; ++mi)
    #pragma unroll
    for (int r = 0; r < 4; ++r) {
      float v0 = acc[mi][0][r], v1 = acc[mi][1][r], v2 = acc[mi][2][r], v3 = acc[mi][3][r];
      float m = fmaxf(fmaxf(v0, v1), fmaxf(v2, v3));
      float s = __expf(v0 - m) + __expf(v1 - m) + __expf(v2 - m) + __expf(v3 - m);
      int R = wm + mi * 16 + q * 4 + r;
      rbuf[R * 33 + (w & 1) * 16 + c16] = make_float2(m, s);
    }
  __syncthreads();
  // ---- rows phase 2: thread t<128 combines row t's 32 partials ----
  if (t < 128) {
    float M = rbuf[t * 33].x;
    #pragma unroll
    for (int x = 1; x < 32; ++x) M = fmaxf(M, rbuf[t * 33 + x].x);
    float S = 0.f;
    #pragma unroll
    for (int x = 0; x < 32; ++x) { float2 p = rbuf[t * 33 + x]; S += p.y * __expf(p.x - M); }
    row_pmax[bn * B_DIM + bm * 128 + t] = M;   // chunk-major: coalesced here AND in combine
    row_psum[bn * B_DIM + bm * 128 + t] = S;
  }
  __syncthreads();
  // ---- cols phase 1: per-lane reduce over 16 (mi,r) values, scatter to cbuf[128][9] ----
  float2* cbuf = (float2*)smem;
  #pragma unroll
  for (int ni = 0; ni < 4; ++ni) {
    float m = -3.0e38f;
    #pragma unroll
    for (int mi = 0; mi < 4; ++mi)
      #pragma unroll
      for (int r = 0; r < 4; ++r) m = fmaxf(m, acc[mi][ni][r]);
    float s = 0.f;
    #pragma unroll
    for (int mi = 0; mi < 4; ++mi)
      #pragma unroll
      for (int r = 0; r < 4; ++r) s += __expf(acc[mi][ni][r] - m);
    int C = wn + ni * 16 + c16;
    cbuf[C * 9 + (w >> 1) * 4 + q] = make_float2(m, s);
  }
  __syncthreads();
  // ---- cols phase 2: thread t<128 combines col t's 8 partials ----
  if (t < 128) {
    float M = cbuf[t * 9].x;
    #pragma unroll
    for (int y = 1; y < 8; ++y) M = fmaxf(M, cbuf[t * 9 + y].x);
    float S = 0.f;
    #pragma unroll
    for (int y = 0; y < 8; ++y) { float2 p = cbuf[t * 9 + y]; S += p.y * __expf(p.x - M); }
    col_pmax[bm * B_DIM + bn * 128 + t] = M;
    col_psum[bm * B_DIM + bn * 128 + t] = S;
  }
}

// ---------------- combine: thread per item; last block (counter) writes d_out ----------------
__global__ __launch_bounds__(256) void combine_kernel(
    const float* __restrict__ row_pmax, const float* __restrict__ row_psum,
    const float* __restrict__ col_pmax, const float* __restrict__ col_psum,
    const float* __restrict__ diagp, const float* __restrict__ log_tau,
    float* __restrict__ acc, unsigned* __restrict__ counter,
    float* __restrict__ out) {
  const int t = threadIdx.x;
  const int item = blockIdx.x * 256 + t;       // 0..4095 rows, 4096..8191 cols
  const float* pm; const float* ps; int i;
  if (item < B_DIM) { pm = row_pmax; ps = row_psum; i = item; }
  else              { pm = col_pmax; ps = col_psum; i = item - B_DIM; }
  float M = pm[i];
  #pragma unroll
  for (int k = 1; k < NCHUNK; ++k) M = fmaxf(M, pm[k * B_DIM + i]);
  float S = 0.f;
  #pragma unroll
  for (int k = 0; k < NCHUNK; ++k) S += ps[k * B_DIM + i] * __expf(pm[k * B_DIM + i] - M);
  float local = M + __logf(S);
  if (blockIdx.x == 0) {                       // fold diag partials (512) into block 0
    float tau = fminf(__expf(log_tau[0]), 100.0f);
    local += -2.0f * tau * (diagp[t] + diagp[t + 256]);
  }
  #pragma unroll
  for (int off = 1; off < 64; off <<= 1) local += __shfl_xor(local, off);
  __shared__ float red[4];
  int w = t >> 6, lane = t & 63;
  if (lane == 0) red[w] = local;
  __syncthreads();
  if (t == 0) {
    atomicAdd(acc, red[0] + red[1] + red[2] + red[3]);
    __threadfence();
    unsigned old = atomicAdd(counter, 1u);
    if (old == 31u) {                          // last of the 32 blocks: finalize
      float v = atomicAdd(acc, 0.0f);          // coherent read after all adds
      out[0] = v * (1.0f / 8192.0f);
    }
  }
}

// ---------------- launch ----------------
extern "C" void kernel_launch(void* const* d_in, const int* in_sizes, int n_in,
                              void* d_out, int out_size, void* d_ws, size_t ws_size,
                              hipStream_t stream) {
  const float* ftir    = (const float*)d_in[0];
  const float* raman   = (const float*)d_in[1];
  // d_in[2] = labels (int64) — unused by the reference output
  const float* log_tau = (const float*)d_in[3];
  float* out = (float*)d_out;

  char* ws = (char*)d_ws;
  // ws layout: Abf 4MiB | Bbf 4MiB | row_pmax 512K | row_psum 512K |
  //            col_pmax 512K | col_psum 512K | diagp 2K | acc 4B | counter 4B
  __bf16* Abf     = (__bf16*)(ws);
  __bf16* Bbf     = (__bf16*)(ws + (4u << 20));
  float* row_pmax = (float*)(ws + (8u << 20));
  float* row_psum = (float*)(ws + (8u << 20) + (512u << 10));
  float* col_pmax = (float*)(ws + (9u << 20));
  float* col_psum = (float*)(ws + (9u << 20) + (512u << 10));
  float* diagp    = (float*)(ws + (10u << 20));
  float* acc      = (float*)(ws + (10u << 20) + 4096);
  unsigned* cnt   = (unsigned*)(ws + (10u << 20) + 4096 + 4);

  cast_diag_kernel<<<512, 256, 0, stream>>>(ftir, raman, Abf, Bbf, diagp, acc, cnt);
  gemm_lse_kernel<<<1024, 256, 0, stream>>>(Abf, Bbf, log_tau,
                                            row_pmax, row_psum, col_pmax, col_psum);
  combine_kernel<<<32, 256, 0, stream>>>(row_pmax, row_psum, col_pmax, col_psum,
                                         diagp, log_tau, acc, cnt, out);
}